// Round 4
// baseline (305.159 us; speedup 1.0000x reference)
//
#include <hip/hip_runtime.h>
#include <cstdint>
#include <cstddef>

#define NHEAD 8
#define SLEN 1024

typedef __bf16 bf16x8 __attribute__((ext_vector_type(8)));
typedef float f32x4 __attribute__((ext_vector_type(4)));

__device__ inline unsigned short f2bf(float f) {
    union { float f; unsigned int u; } v; v.f = f;
    unsigned int u = v.u;
    unsigned int rounded = u + 0x7fffu + ((u >> 16) & 1u);
    return (unsigned short)(rounded >> 16);
}

__device__ inline unsigned int pack2(float a, float b) {
    return (unsigned int)f2bf(a) | ((unsigned int)f2bf(b) << 16);
}

// Convert 8 consecutive f32 at p into a uint4 of 8 packed bf16.
__device__ inline uint4 cvt8(const float* __restrict__ p) {
    float4 a = *reinterpret_cast<const float4*>(p);
    float4 b = *reinterpret_cast<const float4*>(p + 4);
    uint4 r;
    r.x = pack2(a.x, a.y);
    r.y = pack2(a.z, a.w);
    r.z = pack2(b.x, b.y);
    r.w = pack2(b.z, b.w);
    return r;
}

// ---------------- fused QKV projection GEMM ----------------
// Y = X(8192x512) @ W^T, W in {wq,wk,wv} (512x512 row-major [out,in]) selected
// by N-tile. f32 inputs converted to bf16 during LDS staging. Epilogue
// scatters Q/K to (B,H,S,64) bf16 and V transposed to (B,H,64,S) bf16.
// Q pre-scaled by 0.125 (= 1/sqrt(DK)).
__global__ __launch_bounds__(256) void qkv_gemm(
    const float* __restrict__ Xf,
    const float* __restrict__ Wq,
    const float* __restrict__ Wk,
    const float* __restrict__ Wv,
    const float* __restrict__ bq,
    const float* __restrict__ bk,
    const float* __restrict__ bv,
    unsigned short* __restrict__ Qb, unsigned short* __restrict__ Kb,
    unsigned short* __restrict__ Vtb)
{
    __shared__ unsigned short As[128 * 40];
    __shared__ unsigned short Bs[128 * 40];
    const int tid = threadIdx.x;
    const int w = tid >> 6, lane = tid & 63, l15 = lane & 15, quad = lane >> 4;
    const int wm = w & 1, wn = w >> 1;
    const int r0 = blockIdx.x * 128;
    const int ytile = blockIdx.y;          // 0..11 -> global cols 0..1535
    const int c0 = ytile * 128;
    const float* Wsel = (ytile < 4) ? Wq : (ytile < 8) ? Wk : Wv;
    const int cw = c0 & 511;               // row within selected W (tiles never straddle)

    f32x4 zero = {0.0f, 0.0f, 0.0f, 0.0f};
    f32x4 acc[4][4];
    for (int i = 0; i < 4; i++)
        for (int j = 0; j < 4; j++) acc[i][j] = zero;

    // staging: 128 rows x 32 cols = 4096 elems / 256 thr = 16 elems each
    const int srow = tid >> 1;
    const int scol = (tid & 1) * 16;

    for (int k0 = 0; k0 < 512; k0 += 32) {
        const float* pa = Xf + (size_t)(r0 + srow) * 512 + k0 + scol;
        const float* pb = Wsel + (size_t)(cw + srow) * 512 + k0 + scol;
        uint4 a0 = cvt8(pa);
        uint4 a1 = cvt8(pa + 8);
        uint4 b0 = cvt8(pb);
        uint4 b1 = cvt8(pb + 8);
        *reinterpret_cast<uint4*>(As + srow * 40 + scol) = a0;
        *reinterpret_cast<uint4*>(As + srow * 40 + scol + 8) = a1;
        *reinterpret_cast<uint4*>(Bs + srow * 40 + scol) = b0;
        *reinterpret_cast<uint4*>(Bs + srow * 40 + scol + 8) = b1;
        __syncthreads();
        bf16x8 af[4], bfr[4];
        for (int mi = 0; mi < 4; mi++)
            af[mi] = *reinterpret_cast<const bf16x8*>(As + (wm * 64 + mi * 16 + l15) * 40 + quad * 8);
        for (int ni = 0; ni < 4; ni++)
            bfr[ni] = *reinterpret_cast<const bf16x8*>(Bs + (wn * 64 + ni * 16 + l15) * 40 + quad * 8);
        for (int mi = 0; mi < 4; mi++)
            for (int ni = 0; ni < 4; ni++)
                acc[mi][ni] = __builtin_amdgcn_mfma_f32_16x16x32_bf16(af[mi], bfr[ni], acc[mi][ni], 0, 0, 0);
        __syncthreads();
    }

    for (int mi = 0; mi < 4; mi++) {
        int grow_base = r0 + wm * 64 + mi * 16 + quad * 4;
        for (int ni = 0; ni < 4; ni++) {
            int gcol = c0 + wn * 64 + ni * 16 + l15;
            for (int r = 0; r < 4; r++) {
                int grow = grow_base + r;
                float val = acc[mi][ni][r];
                int b = grow >> 10;
                int s = grow & 1023;
                if (gcol < 512) {
                    int h = gcol >> 6, d = gcol & 63;
                    val = (val + bq[gcol]) * 0.125f;  // fold 1/sqrt(DK)
                    Qb[(((size_t)(b * NHEAD + h) << 10) + s) * 64 + d] = f2bf(val);
                } else if (gcol < 1024) {
                    int c = gcol - 512;
                    int h = c >> 6, d = c & 63;
                    val += bk[c];
                    Kb[(((size_t)(b * NHEAD + h) << 10) + s) * 64 + d] = f2bf(val);
                } else {
                    int c = gcol - 1024;
                    int h = c >> 6, d = c & 63;
                    val += bv[c];
                    Vtb[((size_t)(b * NHEAD + h) * 64 + d) * 1024 + s] = f2bf(val);
                }
            }
        }
    }
}

// ---------------- flash attention ----------------
// 1 block per (qtile, h, b). 4 waves x 16 q-rows = 64 q-rows. k-tiles of 64.
__global__ __launch_bounds__(256) void attn_kernel(
    const unsigned short* __restrict__ Qb,
    const unsigned short* __restrict__ Kb,
    const unsigned short* __restrict__ Vtb,
    const float* __restrict__ mask,
    unsigned short* __restrict__ Ob)
{
    __shared__ unsigned short Qs[64 * 72];
    __shared__ unsigned short Ks[64 * 72];
    __shared__ unsigned short Vts[64 * 72];
    __shared__ unsigned short Ps[64 * 72];

    const int tid = threadIdx.x;
    const int w = tid >> 6, lane = tid & 63, l15 = lane & 15, quad = lane >> 4;
    const int qt = blockIdx.x, h = blockIdx.y, b = blockIdx.z;
    const int q0 = qt * 64;
    const size_t bh = (size_t)(b * NHEAD + h);
    const unsigned short* Qg = Qb + bh * SLEN * 64;
    const unsigned short* Kg = Kb + bh * SLEN * 64;
    const unsigned short* Vg = Vtb + bh * 64 * SLEN;
    const float* mbase = mask + (size_t)b * SLEN * SLEN;

    // staging: 64 rows x 64 cols = 4096 elems / 256 thr = 16 elems each
    const int srow = tid >> 2;         // 0..63
    const int scol = (tid & 3) * 16;   // 0,16,32,48

    {
        const unsigned short* pq = Qg + (size_t)(q0 + srow) * 64 + scol;
        uint4 q0v = *reinterpret_cast<const uint4*>(pq);
        uint4 q1v = *reinterpret_cast<const uint4*>(pq + 8);
        *reinterpret_cast<uint4*>(Qs + srow * 72 + scol) = q0v;
        *reinterpret_cast<uint4*>(Qs + srow * 72 + scol + 8) = q1v;
    }

    float m_i[4], l_i[4];
    f32x4 zero = {0.0f, 0.0f, 0.0f, 0.0f};
    f32x4 Oacc[4];
    for (int r = 0; r < 4; r++) { m_i[r] = -3.0e38f; l_i[r] = 0.0f; Oacc[r] = zero; }

    for (int kt = 0; kt < SLEN / 64; kt++) {
        const int k0 = kt * 64;
        __syncthreads();  // previous iter's reads done before restage
        {
            const unsigned short* pk = Kg + (size_t)(k0 + srow) * 64 + scol;
            const unsigned short* pv = Vg + (size_t)srow * SLEN + k0 + scol;
            uint4 k0v = *reinterpret_cast<const uint4*>(pk);
            uint4 k1v = *reinterpret_cast<const uint4*>(pk + 8);
            uint4 v0v = *reinterpret_cast<const uint4*>(pv);
            uint4 v1v = *reinterpret_cast<const uint4*>(pv + 8);
            *reinterpret_cast<uint4*>(Ks + srow * 72 + scol) = k0v;
            *reinterpret_cast<uint4*>(Ks + srow * 72 + scol + 8) = k1v;
            *reinterpret_cast<uint4*>(Vts + srow * 72 + scol) = v0v;
            *reinterpret_cast<uint4*>(Vts + srow * 72 + scol + 8) = v1v;
        }
        __syncthreads();

        // S = Q K^T  (Q pre-scaled)
        bf16x8 aq0 = *reinterpret_cast<const bf16x8*>(Qs + (w * 16 + l15) * 72 + quad * 8);
        bf16x8 aq1 = *reinterpret_cast<const bf16x8*>(Qs + (w * 16 + l15) * 72 + 32 + quad * 8);
        f32x4 sc[4];
        for (int ni = 0; ni < 4; ni++) {
            bf16x8 bk0 = *reinterpret_cast<const bf16x8*>(Ks + (ni * 16 + l15) * 72 + quad * 8);
            bf16x8 bk1 = *reinterpret_cast<const bf16x8*>(Ks + (ni * 16 + l15) * 72 + 32 + quad * 8);
            f32x4 z = zero;
            z = __builtin_amdgcn_mfma_f32_16x16x32_bf16(aq0, bk0, z, 0, 0, 0);
            z = __builtin_amdgcn_mfma_f32_16x16x32_bf16(aq1, bk1, z, 0, 0, 0);
            sc[ni] = z;
        }
        // mask: sc*(1-m) + m*(-1e7); mask is f32 {0,1}
        for (int ni = 0; ni < 4; ni++) {
            int kc = k0 + ni * 16 + l15;
            for (int r = 0; r < 4; r++) {
                int qrow = q0 + w * 16 + quad * 4 + r;
                float mv = mbase[(size_t)qrow * SLEN + kc];
                sc[ni][r] = sc[ni][r] * (1.0f - mv) + mv * (-1.0e7f);
            }
        }
        // online softmax
        float tmax[4];
        for (int r = 0; r < 4; r++) {
            float t = fmaxf(fmaxf(sc[0][r], sc[1][r]), fmaxf(sc[2][r], sc[3][r]));
            t = fmaxf(t, __shfl_xor(t, 1));
            t = fmaxf(t, __shfl_xor(t, 2));
            t = fmaxf(t, __shfl_xor(t, 4));
            t = fmaxf(t, __shfl_xor(t, 8));
            tmax[r] = t;
        }
        float alpha[4], psum[4];
        for (int r = 0; r < 4; r++) {
            float mnew = fmaxf(m_i[r], tmax[r]);
            alpha[r] = __expf(m_i[r] - mnew);
            m_i[r] = mnew;
            psum[r] = 0.0f;
        }
        for (int ni = 0; ni < 4; ni++) {
            for (int r = 0; r < 4; r++) {
                float p = __expf(sc[ni][r] - m_i[r]);
                psum[r] += p;
                Ps[(w * 16 + quad * 4 + r) * 72 + ni * 16 + l15] = f2bf(p);
            }
        }
        for (int r = 0; r < 4; r++) {
            float t = psum[r];
            t += __shfl_xor(t, 1);
            t += __shfl_xor(t, 2);
            t += __shfl_xor(t, 4);
            t += __shfl_xor(t, 8);
            l_i[r] = l_i[r] * alpha[r] + t;
        }
        for (int ni = 0; ni < 4; ni++)
            for (int r = 0; r < 4; r++)
                Oacc[ni][r] *= alpha[r];
        __syncthreads();  // Ps LDS writes drained before A-frag reads

        // O += P V  (Vt layout: B-frag contiguous in key)
        bf16x8 ap0 = *reinterpret_cast<const bf16x8*>(Ps + (w * 16 + l15) * 72 + quad * 8);
        bf16x8 ap1 = *reinterpret_cast<const bf16x8*>(Ps + (w * 16 + l15) * 72 + 32 + quad * 8);
        for (int ni = 0; ni < 4; ni++) {
            bf16x8 bv0 = *reinterpret_cast<const bf16x8*>(Vts + (ni * 16 + l15) * 72 + quad * 8);
            bf16x8 bv1 = *reinterpret_cast<const bf16x8*>(Vts + (ni * 16 + l15) * 72 + 32 + quad * 8);
            Oacc[ni] = __builtin_amdgcn_mfma_f32_16x16x32_bf16(ap0, bv0, Oacc[ni], 0, 0, 0);
            Oacc[ni] = __builtin_amdgcn_mfma_f32_16x16x32_bf16(ap1, bv1, Oacc[ni], 0, 0, 0);
        }
    }

    // epilogue: O/l -> Ob (b, s, h*64+d) bf16
    for (int r = 0; r < 4; r++) {
        float inv = 1.0f / l_i[r];
        int s = q0 + w * 16 + quad * 4 + r;
        for (int ni = 0; ni < 4; ni++) {
            int col = h * 64 + ni * 16 + l15;
            Ob[((size_t)(b * SLEN + s)) * 512 + col] = f2bf(Oacc[ni][r] * inv);
        }
    }
}

// ---------------- output projection GEMM ----------------
__global__ __launch_bounds__(256) void out_gemm(
    const unsigned short* __restrict__ Ob,
    const float* __restrict__ Wof,
    const float* __restrict__ bo,
    float* __restrict__ out)
{
    __shared__ unsigned short As[128 * 40];
    __shared__ unsigned short Bs[128 * 40];
    const int tid = threadIdx.x;
    const int w = tid >> 6, lane = tid & 63, l15 = lane & 15, quad = lane >> 4;
    const int wm = w & 1, wn = w >> 1;
    const int r0 = blockIdx.x * 128;
    const int c0 = blockIdx.y * 128;

    f32x4 zero = {0.0f, 0.0f, 0.0f, 0.0f};
    f32x4 acc[4][4];
    for (int i = 0; i < 4; i++)
        for (int j = 0; j < 4; j++) acc[i][j] = zero;

    const int srow = tid >> 1;
    const int scol = (tid & 1) * 16;

    for (int k0 = 0; k0 < 512; k0 += 32) {
        const unsigned short* pa = Ob + (size_t)(r0 + srow) * 512 + k0 + scol;
        const float* pb = Wof + (size_t)(c0 + srow) * 512 + k0 + scol;
        uint4 a0 = *reinterpret_cast<const uint4*>(pa);
        uint4 a1 = *reinterpret_cast<const uint4*>(pa + 8);
        uint4 b0 = cvt8(pb);
        uint4 b1 = cvt8(pb + 8);
        *reinterpret_cast<uint4*>(As + srow * 40 + scol) = a0;
        *reinterpret_cast<uint4*>(As + srow * 40 + scol + 8) = a1;
        *reinterpret_cast<uint4*>(Bs + srow * 40 + scol) = b0;
        *reinterpret_cast<uint4*>(Bs + srow * 40 + scol + 8) = b1;
        __syncthreads();
        bf16x8 af[4], bfr[4];
        for (int mi = 0; mi < 4; mi++)
            af[mi] = *reinterpret_cast<const bf16x8*>(As + (wm * 64 + mi * 16 + l15) * 40 + quad * 8);
        for (int ni = 0; ni < 4; ni++)
            bfr[ni] = *reinterpret_cast<const bf16x8*>(Bs + (wn * 64 + ni * 16 + l15) * 40 + quad * 8);
        for (int mi = 0; mi < 4; mi++)
            for (int ni = 0; ni < 4; ni++)
                acc[mi][ni] = __builtin_amdgcn_mfma_f32_16x16x32_bf16(af[mi], bfr[ni], acc[mi][ni], 0, 0, 0);
        __syncthreads();
    }

    for (int mi = 0; mi < 4; mi++) {
        int grow_base = r0 + wm * 64 + mi * 16 + quad * 4;
        for (int ni = 0; ni < 4; ni++) {
            int gcol = c0 + wn * 64 + ni * 16 + l15;
            float bias = bo[gcol];
            for (int r = 0; r < 4; r++) {
                int grow = grow_base + r;
                out[(size_t)grow * 512 + gcol] = acc[mi][ni][r] + bias;
            }
        }
    }
}

extern "C" void kernel_launch(void* const* d_in, const int* in_sizes, int n_in,
                              void* d_out, int out_size, void* d_ws, size_t ws_size,
                              hipStream_t stream) {
    (void)in_sizes; (void)n_in; (void)out_size; (void)ws_size;
    // f32 dataset per the reference: all inputs/outputs float32.
    const float* x    = (const float*)d_in[0];
    const float* mask = (const float*)d_in[1];
    const float* wq   = (const float*)d_in[2];
    const float* bq   = (const float*)d_in[3];
    const float* wk   = (const float*)d_in[4];
    const float* bk   = (const float*)d_in[5];
    const float* wv   = (const float*)d_in[6];
    const float* bv   = (const float*)d_in[7];
    const float* wo   = (const float*)d_in[8];
    const float* bo   = (const float*)d_in[9];
    float* out = (float*)d_out;

    char* ws = (char*)d_ws;
    unsigned short* Qb   = (unsigned short*)(ws);                  // (B,H,S,64)  8 MB bf16
    unsigned short* Kb   = (unsigned short*)(ws + (8u << 20));     // (B,H,S,64)  8 MB bf16
    unsigned short* Vtb  = (unsigned short*)(ws + (16u << 20));    // (B,H,64,S)  8 MB bf16
    unsigned short* Obuf = (unsigned short*)(ws + (24u << 20));    // (B,S,512)   8 MB bf16

    qkv_gemm<<<dim3(64, 12), 256, 0, stream>>>(x, wq, wk, wv, bq, bk, bv, Qb, Kb, Vtb);
    attn_kernel<<<dim3(16, 8, 8), 256, 0, stream>>>(Qb, Kb, Vtb, mask, Obuf);
    out_gemm<<<dim3(64, 4), 256, 0, stream>>>(Obuf, wo, bo, out);
}

// Round 5
// 303.183 us; speedup vs baseline: 1.0065x; 1.0065x over previous
//
#include <hip/hip_runtime.h>
#include <cstdint>
#include <cstddef>

#define NHEAD 8
#define SLEN 1024

typedef __bf16 bf16x8 __attribute__((ext_vector_type(8)));
typedef float f32x4 __attribute__((ext_vector_type(4)));

__device__ inline unsigned short f2bf(float f) {
    union { float f; unsigned int u; } v; v.f = f;
    unsigned int u = v.u;
    unsigned int rounded = u + 0x7fffu + ((u >> 16) & 1u);
    return (unsigned short)(rounded >> 16);
}

__device__ inline unsigned int pack2(float a, float b) {
    return (unsigned int)f2bf(a) | ((unsigned int)f2bf(b) << 16);
}

// Convert 8 consecutive f32 at p into a uint4 of 8 packed bf16.
__device__ inline uint4 cvt8(const float* __restrict__ p) {
    float4 a = *reinterpret_cast<const float4*>(p);
    float4 b = *reinterpret_cast<const float4*>(p + 4);
    uint4 r;
    r.x = pack2(a.x, a.y);
    r.y = pack2(a.z, a.w);
    r.z = pack2(b.x, b.y);
    r.w = pack2(b.z, b.w);
    return r;
}

// ---------------- fused QKV projection GEMM ----------------
// Y = X(8192x512) @ W^T, W in {wq,wk,wv} selected by N-tile. f32 inputs
// converted to bf16 during LDS staging. Q/K scatter to (B,H,S,64) bf16;
// V goes through an LDS transpose and stores coalesced to (B,H,64,S) bf16.
// Q pre-scaled by 0.125 (= 1/sqrt(DK)).
__global__ __launch_bounds__(256) void qkv_gemm(
    const float* __restrict__ Xf,
    const float* __restrict__ Wq,
    const float* __restrict__ Wk,
    const float* __restrict__ Wv,
    const float* __restrict__ bq,
    const float* __restrict__ bk,
    const float* __restrict__ bv,
    unsigned short* __restrict__ Qb, unsigned short* __restrict__ Kb,
    unsigned short* __restrict__ Vtb)
{
    __shared__ unsigned short As[2 * 128 * 40];   // also reused as transpose buf
    unsigned short* Bs = As + 128 * 40;
    const int tid = threadIdx.x;
    const int w = tid >> 6, lane = tid & 63, l15 = lane & 15, quad = lane >> 4;
    const int wm = w & 1, wn = w >> 1;
    const int r0 = blockIdx.x * 128;
    const int ytile = blockIdx.y;          // 0..11 -> global cols 0..1535
    const int c0 = ytile * 128;
    const float* Wsel = (ytile < 4) ? Wq : (ytile < 8) ? Wk : Wv;
    const int cw = c0 & 511;               // row within selected W

    f32x4 zero = {0.0f, 0.0f, 0.0f, 0.0f};
    f32x4 acc[4][4];
    for (int i = 0; i < 4; i++)
        for (int j = 0; j < 4; j++) acc[i][j] = zero;

    const int srow = tid >> 1;
    const int scol = (tid & 1) * 16;

    for (int k0 = 0; k0 < 512; k0 += 32) {
        const float* pa = Xf + (size_t)(r0 + srow) * 512 + k0 + scol;
        const float* pb = Wsel + (size_t)(cw + srow) * 512 + k0 + scol;
        uint4 a0 = cvt8(pa);
        uint4 a1 = cvt8(pa + 8);
        uint4 b0 = cvt8(pb);
        uint4 b1 = cvt8(pb + 8);
        *reinterpret_cast<uint4*>(As + srow * 40 + scol) = a0;
        *reinterpret_cast<uint4*>(As + srow * 40 + scol + 8) = a1;
        *reinterpret_cast<uint4*>(Bs + srow * 40 + scol) = b0;
        *reinterpret_cast<uint4*>(Bs + srow * 40 + scol + 8) = b1;
        __syncthreads();
        bf16x8 af[4], bfr[4];
        for (int mi = 0; mi < 4; mi++)
            af[mi] = *reinterpret_cast<const bf16x8*>(As + (wm * 64 + mi * 16 + l15) * 40 + quad * 8);
        for (int ni = 0; ni < 4; ni++)
            bfr[ni] = *reinterpret_cast<const bf16x8*>(Bs + (wn * 64 + ni * 16 + l15) * 40 + quad * 8);
        for (int mi = 0; mi < 4; mi++)
            for (int ni = 0; ni < 4; ni++)
                acc[mi][ni] = __builtin_amdgcn_mfma_f32_16x16x32_bf16(af[mi], bfr[ni], acc[mi][ni], 0, 0, 0);
        __syncthreads();
    }

    if (ytile < 8) {
        // Q / K epilogue: scatter to (B,H,S,64)
        for (int mi = 0; mi < 4; mi++) {
            int grow_base = r0 + wm * 64 + mi * 16 + quad * 4;
            for (int ni = 0; ni < 4; ni++) {
                int gcol = c0 + wn * 64 + ni * 16 + l15;
                for (int r = 0; r < 4; r++) {
                    int grow = grow_base + r;
                    float val = acc[mi][ni][r];
                    int b = grow >> 10;
                    int s = grow & 1023;
                    if (gcol < 512) {
                        int h = gcol >> 6, d = gcol & 63;
                        val = (val + bq[gcol]) * 0.125f;  // fold 1/sqrt(DK)
                        Qb[(((size_t)(b * NHEAD + h) << 10) + s) * 64 + d] = f2bf(val);
                    } else {
                        int c = gcol - 512;
                        int h = c >> 6, d = c & 63;
                        val += bk[c];
                        Kb[(((size_t)(b * NHEAD + h) << 10) + s) * 64 + d] = f2bf(val);
                    }
                }
            }
        }
    } else {
        // V epilogue: transpose via LDS, then coalesced store to (B,H,64,S)
        const int h_base = (c0 - 1024) >> 6;   // 0,2,4,6 (block covers 2 heads)
        const int bb = r0 >> 10;
        const int s_base = r0 & 1023;
        for (int p = 0; p < 2; p++) {
            __syncthreads();
            if (wn == p) {
                for (int mi = 0; mi < 4; mi++) {
                    for (int ni = 0; ni < 4; ni++) {
                        int d_local = ni * 16 + l15;
                        float bias = bv[(h_base + p) * 64 + d_local];
                        for (int r = 0; r < 4; r++) {
                            int s_local = wm * 64 + mi * 16 + quad * 4 + r;
                            As[d_local * 136 + s_local] = f2bf(acc[mi][ni][r] + bias);
                        }
                    }
                }
            }
            __syncthreads();
            // 64 d-rows x 128 s, coalesced along s
            int sidx = (tid & 15) * 8;
            int drow = tid >> 4;                 // 0..15
            for (int dg = 0; dg < 4; dg++) {
                int d = dg * 16 + drow;
                size_t dst = ((size_t)(bb * NHEAD + h_base + p) * 64 + d) * 1024 + s_base;
                uint4 vv = *reinterpret_cast<const uint4*>(As + d * 136 + sidx);
                *reinterpret_cast<uint4*>(Vtb + dst + sidx) = vv;
            }
        }
    }
}

// ---------------- flash attention (barrier-free waves) ----------------
// Each wave owns 16 q-rows independently. Q/K/V fragments load directly from
// global (L1/L2-served; waves in a block and q-blocks of same (b,h) share
// K/V). Only P round-trips through wave-private LDS (no __syncthreads).
__global__ __launch_bounds__(256) void attn_kernel(
    const unsigned short* __restrict__ Qb,
    const unsigned short* __restrict__ Kb,
    const unsigned short* __restrict__ Vtb,
    const float* __restrict__ mask,
    unsigned short* __restrict__ Ob)
{
    __shared__ __bf16 Ps[4 * 16 * 72];

    const int tid = threadIdx.x;
    const int w = tid >> 6, lane = tid & 63, l15 = lane & 15, quad = lane >> 4;
    const int qt = blockIdx.x, h = blockIdx.y, b = blockIdx.z;
    const int q0 = qt * 64 + w * 16;           // this wave's 16 q-rows
    const size_t bh = (size_t)(b * NHEAD + h);
    const unsigned short* Qg = Qb + bh * SLEN * 64;
    const unsigned short* Kg = Kb + bh * SLEN * 64;
    const unsigned short* Vg = Vtb + bh * 64 * SLEN;
    const float* mbase = mask + (size_t)b * SLEN * SLEN;
    __bf16* Pw = Ps + w * 16 * 72;

    // Q A-fragments: lane l15 = q-row, k contiguous 8 at quad*8 (+32)
    bf16x8 aq0 = *reinterpret_cast<const bf16x8*>(Qg + (size_t)(q0 + l15) * 64 + quad * 8);
    bf16x8 aq1 = *reinterpret_cast<const bf16x8*>(Qg + (size_t)(q0 + l15) * 64 + 32 + quad * 8);

    float m_i[4], l_i[4];
    f32x4 zero = {0.0f, 0.0f, 0.0f, 0.0f};
    f32x4 Oacc[4];
    for (int r = 0; r < 4; r++) { m_i[r] = -3.0e38f; l_i[r] = 0.0f; Oacc[r] = zero; }

    for (int kt = 0; kt < SLEN / 64; kt++) {
        const int k0 = kt * 64;

        // S = Q K^T : K B-frag lane l15 = key row, k contiguous at quad*8
        f32x4 sc[4];
        for (int ni = 0; ni < 4; ni++) {
            const unsigned short* kp = Kg + (size_t)(k0 + ni * 16 + l15) * 64 + quad * 8;
            bf16x8 bk0 = *reinterpret_cast<const bf16x8*>(kp);
            bf16x8 bk1 = *reinterpret_cast<const bf16x8*>(kp + 32);
            f32x4 z = zero;
            z = __builtin_amdgcn_mfma_f32_16x16x32_bf16(aq0, bk0, z, 0, 0, 0);
            z = __builtin_amdgcn_mfma_f32_16x16x32_bf16(aq1, bk1, z, 0, 0, 0);
            sc[ni] = z;
        }
        // mask: masked (mv!=0) -> -1e7
        for (int ni = 0; ni < 4; ni++) {
            int kc = k0 + ni * 16 + l15;
            for (int r = 0; r < 4; r++) {
                int qrow = q0 + quad * 4 + r;
                float mv = mbase[(size_t)qrow * SLEN + kc];
                sc[ni][r] = (mv == 0.0f) ? sc[ni][r] : -1.0e7f;
            }
        }
        // online softmax (rows = quad*4+r, reduce over 16 cols = l15 lanes)
        float tmax[4];
        for (int r = 0; r < 4; r++) {
            float t = fmaxf(fmaxf(sc[0][r], sc[1][r]), fmaxf(sc[2][r], sc[3][r]));
            t = fmaxf(t, __shfl_xor(t, 1));
            t = fmaxf(t, __shfl_xor(t, 2));
            t = fmaxf(t, __shfl_xor(t, 4));
            t = fmaxf(t, __shfl_xor(t, 8));
            tmax[r] = t;
        }
        float alpha[4], psum[4];
        for (int r = 0; r < 4; r++) {
            float mnew = fmaxf(m_i[r], tmax[r]);
            alpha[r] = __expf(m_i[r] - mnew);
            m_i[r] = mnew;
            psum[r] = 0.0f;
        }
        for (int ni = 0; ni < 4; ni++) {
            for (int r = 0; r < 4; r++) {
                float p = __expf(sc[ni][r] - m_i[r]);
                psum[r] += p;
                Pw[(quad * 4 + r) * 72 + ni * 16 + l15] = (__bf16)p;
            }
        }
        for (int r = 0; r < 4; r++) {
            float t = psum[r];
            t += __shfl_xor(t, 1);
            t += __shfl_xor(t, 2);
            t += __shfl_xor(t, 4);
            t += __shfl_xor(t, 8);
            l_i[r] = l_i[r] * alpha[r] + t;
        }
        for (int ni = 0; ni < 4; ni++)
            for (int r = 0; r < 4; r++)
                Oacc[ni][r] *= alpha[r];

        // P A-frag from wave-private LDS (compiler inserts lgkmcnt wait)
        bf16x8 ap0 = *reinterpret_cast<const bf16x8*>(Pw + l15 * 72 + quad * 8);
        bf16x8 ap1 = *reinterpret_cast<const bf16x8*>(Pw + l15 * 72 + 32 + quad * 8);
        // V B-frag: lane l15 = d col, keys contiguous at quad*8 (V^T layout)
        for (int ni = 0; ni < 4; ni++) {
            const unsigned short* vp = Vg + (size_t)(ni * 16 + l15) * SLEN + k0 + quad * 8;
            bf16x8 bv0 = *reinterpret_cast<const bf16x8*>(vp);
            bf16x8 bv1 = *reinterpret_cast<const bf16x8*>(vp + 32);
            Oacc[ni] = __builtin_amdgcn_mfma_f32_16x16x32_bf16(ap0, bv0, Oacc[ni], 0, 0, 0);
            Oacc[ni] = __builtin_amdgcn_mfma_f32_16x16x32_bf16(ap1, bv1, Oacc[ni], 0, 0, 0);
        }
    }

    // epilogue: O/l -> Ob (b, s, h*64+d) bf16
    for (int r = 0; r < 4; r++) {
        float inv = 1.0f / l_i[r];
        int s = q0 + quad * 4 + r;
        for (int ni = 0; ni < 4; ni++) {
            int col = h * 64 + ni * 16 + l15;
            Ob[((size_t)(b * SLEN + s)) * 512 + col] = f2bf(Oacc[ni][r] * inv);
        }
    }
}

// ---------------- output projection GEMM ----------------
__global__ __launch_bounds__(256) void out_gemm(
    const unsigned short* __restrict__ Ob,
    const float* __restrict__ Wof,
    const float* __restrict__ bo,
    float* __restrict__ out)
{
    __shared__ unsigned short As[128 * 40];
    __shared__ unsigned short Bs[128 * 40];
    const int tid = threadIdx.x;
    const int w = tid >> 6, lane = tid & 63, l15 = lane & 15, quad = lane >> 4;
    const int wm = w & 1, wn = w >> 1;
    const int r0 = blockIdx.x * 128;
    const int c0 = blockIdx.y * 128;

    f32x4 zero = {0.0f, 0.0f, 0.0f, 0.0f};
    f32x4 acc[4][4];
    for (int i = 0; i < 4; i++)
        for (int j = 0; j < 4; j++) acc[i][j] = zero;

    const int srow = tid >> 1;
    const int scol = (tid & 1) * 16;

    for (int k0 = 0; k0 < 512; k0 += 32) {
        const unsigned short* pa = Ob + (size_t)(r0 + srow) * 512 + k0 + scol;
        const float* pb = Wof + (size_t)(c0 + srow) * 512 + k0 + scol;
        uint4 a0 = *reinterpret_cast<const uint4*>(pa);
        uint4 a1 = *reinterpret_cast<const uint4*>(pa + 8);
        uint4 b0 = cvt8(pb);
        uint4 b1 = cvt8(pb + 8);
        *reinterpret_cast<uint4*>(As + srow * 40 + scol) = a0;
        *reinterpret_cast<uint4*>(As + srow * 40 + scol + 8) = a1;
        *reinterpret_cast<uint4*>(Bs + srow * 40 + scol) = b0;
        *reinterpret_cast<uint4*>(Bs + srow * 40 + scol + 8) = b1;
        __syncthreads();
        bf16x8 af[4], bfr[4];
        for (int mi = 0; mi < 4; mi++)
            af[mi] = *reinterpret_cast<const bf16x8*>(As + (wm * 64 + mi * 16 + l15) * 40 + quad * 8);
        for (int ni = 0; ni < 4; ni++)
            bfr[ni] = *reinterpret_cast<const bf16x8*>(Bs + (wn * 64 + ni * 16 + l15) * 40 + quad * 8);
        for (int mi = 0; mi < 4; mi++)
            for (int ni = 0; ni < 4; ni++)
                acc[mi][ni] = __builtin_amdgcn_mfma_f32_16x16x32_bf16(af[mi], bfr[ni], acc[mi][ni], 0, 0, 0);
        __syncthreads();
    }

    for (int mi = 0; mi < 4; mi++) {
        int grow_base = r0 + wm * 64 + mi * 16 + quad * 4;
        for (int ni = 0; ni < 4; ni++) {
            int gcol = c0 + wn * 64 + ni * 16 + l15;
            float bias = bo[gcol];
            for (int r = 0; r < 4; r++) {
                int grow = grow_base + r;
                out[(size_t)grow * 512 + gcol] = acc[mi][ni][r] + bias;
            }
        }
    }
}

extern "C" void kernel_launch(void* const* d_in, const int* in_sizes, int n_in,
                              void* d_out, int out_size, void* d_ws, size_t ws_size,
                              hipStream_t stream) {
    (void)in_sizes; (void)n_in; (void)out_size; (void)ws_size;
    const float* x    = (const float*)d_in[0];
    const float* mask = (const float*)d_in[1];
    const float* wq   = (const float*)d_in[2];
    const float* bq   = (const float*)d_in[3];
    const float* wk   = (const float*)d_in[4];
    const float* bk   = (const float*)d_in[5];
    const float* wv   = (const float*)d_in[6];
    const float* bv   = (const float*)d_in[7];
    const float* wo   = (const float*)d_in[8];
    const float* bo   = (const float*)d_in[9];
    float* out = (float*)d_out;

    char* ws = (char*)d_ws;
    unsigned short* Qb   = (unsigned short*)(ws);                  // (B,H,S,64)  8 MB bf16
    unsigned short* Kb   = (unsigned short*)(ws + (8u << 20));     // (B,H,S,64)  8 MB bf16
    unsigned short* Vtb  = (unsigned short*)(ws + (16u << 20));    // (B,H,64,S)  8 MB bf16
    unsigned short* Obuf = (unsigned short*)(ws + (24u << 20));    // (B,S,512)   8 MB bf16

    qkv_gemm<<<dim3(64, 12), 256, 0, stream>>>(x, wq, wk, wv, bq, bk, bv, Qb, Kb, Vtb);
    attn_kernel<<<dim3(16, 8, 8), 256, 0, stream>>>(Qb, Kb, Vtb, mask, Obuf);
    out_gemm<<<dim3(64, 4), 256, 0, stream>>>(Obuf, wo, bo, out);
}

// Round 6
// 294.906 us; speedup vs baseline: 1.0348x; 1.0281x over previous
//
#include <hip/hip_runtime.h>
#include <cstdint>
#include <cstddef>

#define NHEAD 8
#define SLEN 1024

typedef __bf16 bf16x8 __attribute__((ext_vector_type(8)));
typedef float f32x4 __attribute__((ext_vector_type(4)));

__device__ inline unsigned short f2bf(float f) {
    union { float f; unsigned int u; } v; v.f = f;
    unsigned int u = v.u;
    unsigned int rounded = u + 0x7fffu + ((u >> 16) & 1u);
    return (unsigned short)(rounded >> 16);
}

__device__ inline unsigned int pack2(float a, float b) {
    return (unsigned int)f2bf(a) | ((unsigned int)f2bf(b) << 16);
}

__device__ inline uint4 cvt8(const float* __restrict__ p) {
    float4 a = *reinterpret_cast<const float4*>(p);
    float4 b = *reinterpret_cast<const float4*>(p + 4);
    uint4 r;
    r.x = pack2(a.x, a.y);
    r.y = pack2(a.z, a.w);
    r.z = pack2(b.x, b.y);
    r.w = pack2(b.z, b.w);
    return r;
}

// ---------------- mask bit-packing ----------------
// mask f32 {0,1} (8,1024,1024) -> 1 bit per element, u64 per 64-col segment.
// bits[(b*1024+row)*16 + seg] bit l = mask[b][row][seg*64+l] != 0.
__global__ __launch_bounds__(256) void pack_mask(
    const float* __restrict__ mask, unsigned long long* __restrict__ bits)
{
    int wid = (blockIdx.x * 256 + threadIdx.x) >> 6;   // global wave id
    int lane = threadIdx.x & 63;
    for (int s = 0; s < 4; s++) {
        size_t seg = (size_t)wid * 4 + s;
        float mv = mask[seg * 64 + lane];
        unsigned long long bb = __ballot(mv != 0.0f);
        if (lane == 0) bits[seg] = bb;
    }
}

// ---------------- f32 -> bf16 pre-cast (X + 4 weights) ----------------
__global__ __launch_bounds__(256) void cast_all(
    const float* __restrict__ X,
    const float* __restrict__ wq, const float* __restrict__ wk,
    const float* __restrict__ wv, const float* __restrict__ wo,
    unsigned short* __restrict__ Xb, unsigned short* __restrict__ Wc)
{
    int y = blockIdx.y;
    const float* src;
    unsigned short* dst;
    int n;
    if (y == 0) { src = X;  dst = Xb; n = 8192 * 512; }
    else {
        src = (y == 1) ? wq : (y == 2) ? wk : (y == 3) ? wv : wo;
        dst = Wc + (size_t)(y - 1) * 262144;
        n = 262144;
    }
    int i = (blockIdx.x * 256 + threadIdx.x) * 8;
    if (i + 8 <= n) {
        uint4 v = cvt8(src + i);
        *reinterpret_cast<uint4*>(dst + i) = v;
    }
}

// ---------------- fused QKV projection GEMM (bf16 in) ----------------
// Y = Xb(8192x512) @ W^T, W selected from Wc by N-tile. Q/K epilogue goes
// through LDS -> fully coalesced 16B stores to (B,H,S,64). V transposes via
// LDS to (B,H,64,S). Q pre-scaled by 0.125.
__global__ __launch_bounds__(256) void qkv_gemm(
    const unsigned short* __restrict__ Xb,
    const unsigned short* __restrict__ Wc,
    const float* __restrict__ bq, const float* __restrict__ bk,
    const float* __restrict__ bv,
    unsigned short* __restrict__ Qb, unsigned short* __restrict__ Kb,
    unsigned short* __restrict__ Vtb)
{
    __shared__ unsigned short As[17408];   // k-loop: [0,5120) A, [5120,10240) B; epilogue: 128x136
    unsigned short* Bs = As + 128 * 40;
    const int tid = threadIdx.x;
    const int w = tid >> 6, lane = tid & 63, l15 = lane & 15, quad = lane >> 4;
    const int wm = w & 1, wn = w >> 1;
    const int r0 = blockIdx.x * 128;
    const int ytile = blockIdx.y;          // 0..11
    const int c0 = ytile * 128;
    const unsigned short* Wsel = Wc + (size_t)(ytile >> 2) * 262144;
    const int cw = c0 & 511;

    f32x4 zero = {0.0f, 0.0f, 0.0f, 0.0f};
    f32x4 acc[4][4];
    for (int i = 0; i < 4; i++)
        for (int j = 0; j < 4; j++) acc[i][j] = zero;

    const int srow = tid >> 1;
    const int scol = (tid & 1) * 16;

    for (int k0 = 0; k0 < 512; k0 += 32) {
        const unsigned short* pa = Xb + (size_t)(r0 + srow) * 512 + k0 + scol;
        const unsigned short* pb = Wsel + (size_t)(cw + srow) * 512 + k0 + scol;
        uint4 a0 = *reinterpret_cast<const uint4*>(pa);
        uint4 a1 = *reinterpret_cast<const uint4*>(pa + 8);
        uint4 b0 = *reinterpret_cast<const uint4*>(pb);
        uint4 b1 = *reinterpret_cast<const uint4*>(pb + 8);
        *reinterpret_cast<uint4*>(As + srow * 40 + scol) = a0;
        *reinterpret_cast<uint4*>(As + srow * 40 + scol + 8) = a1;
        *reinterpret_cast<uint4*>(Bs + srow * 40 + scol) = b0;
        *reinterpret_cast<uint4*>(Bs + srow * 40 + scol + 8) = b1;
        __syncthreads();
        bf16x8 af[4], bfr[4];
        for (int mi = 0; mi < 4; mi++)
            af[mi] = *reinterpret_cast<const bf16x8*>(As + (wm * 64 + mi * 16 + l15) * 40 + quad * 8);
        for (int ni = 0; ni < 4; ni++)
            bfr[ni] = *reinterpret_cast<const bf16x8*>(Bs + (wn * 64 + ni * 16 + l15) * 40 + quad * 8);
        for (int mi = 0; mi < 4; mi++)
            for (int ni = 0; ni < 4; ni++)
                acc[mi][ni] = __builtin_amdgcn_mfma_f32_16x16x32_bf16(af[mi], bfr[ni], acc[mi][ni], 0, 0, 0);
        __syncthreads();
    }

    const int bb = r0 >> 10;
    const int s0 = r0 & 1023;

    if (ytile < 8) {
        // Q / K epilogue: C-tile -> LDS (128x136) -> coalesced 16B stores
        const bool isQ = (ytile < 4);
        const float* bias = isQ ? bq : bk;
        unsigned short* dst = isQ ? Qb : Kb;
        const float scale = isQ ? 0.125f : 1.0f;
        const int h0 = cw >> 6;            // first head covered (block spans 2 heads)
        for (int mi = 0; mi < 4; mi++) {
            for (int ni = 0; ni < 4; ni++) {
                int col = wn * 64 + ni * 16 + l15;
                float bsv = bias[cw + col];
                for (int r = 0; r < 4; r++) {
                    int s_local = wm * 64 + mi * 16 + quad * 4 + r;
                    As[s_local * 136 + col] = f2bf((acc[mi][ni][r] + bsv) * scale);
                }
            }
        }
        __syncthreads();
        for (int p = 0; p < 2; p++) {
            size_t base = (((size_t)(bb * NHEAD + h0 + p)) << 10) + s0;
            for (int i = 0; i < 4; i++) {
                int flat = i * 256 + tid;      // 0..1023
                int row = flat >> 3;           // 0..127
                int ch = flat & 7;             // 16B chunk in 64-col head slice
                uint4 vv = *reinterpret_cast<const uint4*>(As + row * 136 + p * 64 + ch * 8);
                *reinterpret_cast<uint4*>(dst + (base + row) * 64 + ch * 8) = vv;
            }
        }
    } else {
        // V epilogue: transpose via LDS, coalesced store to (B,H,64,S)
        const int h_base = (c0 - 1024) >> 6;   // 0,2,4,6
        for (int p = 0; p < 2; p++) {
            __syncthreads();
            if (wn == p) {
                for (int mi = 0; mi < 4; mi++) {
                    for (int ni = 0; ni < 4; ni++) {
                        int d_local = ni * 16 + l15;
                        float bias = bv[(h_base + p) * 64 + d_local];
                        for (int r = 0; r < 4; r++) {
                            int s_local = wm * 64 + mi * 16 + quad * 4 + r;
                            As[d_local * 136 + s_local] = f2bf(acc[mi][ni][r] + bias);
                        }
                    }
                }
            }
            __syncthreads();
            int sidx = (tid & 15) * 8;
            int drow = tid >> 4;
            for (int dg = 0; dg < 4; dg++) {
                int d = dg * 16 + drow;
                size_t dst = ((size_t)(bb * NHEAD + h_base + p) * 64 + d) * 1024 + s0;
                uint4 vv = *reinterpret_cast<const uint4*>(As + d * 136 + sidx);
                *reinterpret_cast<uint4*>(Vtb + dst + sidx) = vv;
            }
        }
    }
}

// ---------------- flash attention (barrier-free waves, bit mask) ----------------
__global__ __launch_bounds__(256) void attn_kernel(
    const unsigned short* __restrict__ Qb,
    const unsigned short* __restrict__ Kb,
    const unsigned short* __restrict__ Vtb,
    const unsigned long long* __restrict__ Mbits,
    unsigned short* __restrict__ Ob)
{
    __shared__ __bf16 Ps[4 * 16 * 72];

    const int tid = threadIdx.x;
    const int w = tid >> 6, lane = tid & 63, l15 = lane & 15, quad = lane >> 4;
    const int qt = blockIdx.x, h = blockIdx.y, b = blockIdx.z;
    const int q0 = qt * 64 + w * 16;
    const size_t bh = (size_t)(b * NHEAD + h);
    const unsigned short* Qg = Qb + bh * SLEN * 64;
    const unsigned short* Kg = Kb + bh * SLEN * 64;
    const unsigned short* Vg = Vtb + bh * 64 * SLEN;
    const unsigned long long* mrow = Mbits + (size_t)b * SLEN * 16;
    __bf16* Pw = Ps + w * 16 * 72;

    bf16x8 aq0 = *reinterpret_cast<const bf16x8*>(Qg + (size_t)(q0 + l15) * 64 + quad * 8);
    bf16x8 aq1 = *reinterpret_cast<const bf16x8*>(Qg + (size_t)(q0 + l15) * 64 + 32 + quad * 8);

    float m_i[4], l_i[4];
    f32x4 zero = {0.0f, 0.0f, 0.0f, 0.0f};
    f32x4 Oacc[4];
    for (int r = 0; r < 4; r++) { m_i[r] = -3.0e38f; l_i[r] = 0.0f; Oacc[r] = zero; }

    for (int kt = 0; kt < SLEN / 64; kt++) {
        const int k0 = kt * 64;

        // mask words for this wave's 4 rows (per quad), pre-shifted by l15
        unsigned long long mw[4];
        for (int r = 0; r < 4; r++)
            mw[r] = mrow[(size_t)(q0 + quad * 4 + r) * 16 + kt] >> l15;

        // S = Q K^T
        f32x4 sc[4];
        for (int ni = 0; ni < 4; ni++) {
            const unsigned short* kp = Kg + (size_t)(k0 + ni * 16 + l15) * 64 + quad * 8;
            bf16x8 bk0 = *reinterpret_cast<const bf16x8*>(kp);
            bf16x8 bk1 = *reinterpret_cast<const bf16x8*>(kp + 32);
            f32x4 z = zero;
            z = __builtin_amdgcn_mfma_f32_16x16x32_bf16(aq0, bk0, z, 0, 0, 0);
            z = __builtin_amdgcn_mfma_f32_16x16x32_bf16(aq1, bk1, z, 0, 0, 0);
            sc[ni] = z;
        }
        // apply mask bits: bit (ni*16) of mw[r]
        for (int r = 0; r < 4; r++) {
            unsigned int lo = (unsigned int)mw[r];
            unsigned int hi = (unsigned int)(mw[r] >> 32);
            sc[0][r] = (lo & 1u)         ? -1.0e7f : sc[0][r];
            sc[1][r] = ((lo >> 16) & 1u) ? -1.0e7f : sc[1][r];
            sc[2][r] = (hi & 1u)         ? -1.0e7f : sc[2][r];
            sc[3][r] = ((hi >> 16) & 1u) ? -1.0e7f : sc[3][r];
        }
        // online softmax
        float tmax[4];
        for (int r = 0; r < 4; r++) {
            float t = fmaxf(fmaxf(sc[0][r], sc[1][r]), fmaxf(sc[2][r], sc[3][r]));
            t = fmaxf(t, __shfl_xor(t, 1));
            t = fmaxf(t, __shfl_xor(t, 2));
            t = fmaxf(t, __shfl_xor(t, 4));
            t = fmaxf(t, __shfl_xor(t, 8));
            tmax[r] = t;
        }
        float alpha[4], psum[4];
        for (int r = 0; r < 4; r++) {
            float mnew = fmaxf(m_i[r], tmax[r]);
            alpha[r] = __expf(m_i[r] - mnew);
            m_i[r] = mnew;
            psum[r] = 0.0f;
        }
        for (int ni = 0; ni < 4; ni++) {
            for (int r = 0; r < 4; r++) {
                float p = __expf(sc[ni][r] - m_i[r]);
                psum[r] += p;
                Pw[(quad * 4 + r) * 72 + ni * 16 + l15] = (__bf16)p;
            }
        }
        for (int r = 0; r < 4; r++) {
            float t = psum[r];
            t += __shfl_xor(t, 1);
            t += __shfl_xor(t, 2);
            t += __shfl_xor(t, 4);
            t += __shfl_xor(t, 8);
            l_i[r] = l_i[r] * alpha[r] + t;
        }
        for (int ni = 0; ni < 4; ni++)
            for (int r = 0; r < 4; r++)
                Oacc[ni][r] *= alpha[r];

        bf16x8 ap0 = *reinterpret_cast<const bf16x8*>(Pw + l15 * 72 + quad * 8);
        bf16x8 ap1 = *reinterpret_cast<const bf16x8*>(Pw + l15 * 72 + 32 + quad * 8);
        for (int ni = 0; ni < 4; ni++) {
            const unsigned short* vp = Vg + (size_t)(ni * 16 + l15) * SLEN + k0 + quad * 8;
            bf16x8 bv0 = *reinterpret_cast<const bf16x8*>(vp);
            bf16x8 bv1 = *reinterpret_cast<const bf16x8*>(vp + 32);
            Oacc[ni] = __builtin_amdgcn_mfma_f32_16x16x32_bf16(ap0, bv0, Oacc[ni], 0, 0, 0);
            Oacc[ni] = __builtin_amdgcn_mfma_f32_16x16x32_bf16(ap1, bv1, Oacc[ni], 0, 0, 0);
        }
    }

    for (int r = 0; r < 4; r++) {
        float inv = 1.0f / l_i[r];
        int s = q0 + quad * 4 + r;
        for (int ni = 0; ni < 4; ni++) {
            int col = h * 64 + ni * 16 + l15;
            Ob[((size_t)(b * SLEN + s)) * 512 + col] = f2bf(Oacc[ni][r] * inv);
        }
    }
}

// ---------------- output projection GEMM (bf16 in, f32 out) ----------------
__global__ __launch_bounds__(256) void out_gemm(
    const unsigned short* __restrict__ Ob,
    const unsigned short* __restrict__ Wob,
    const float* __restrict__ bo,
    float* __restrict__ out)
{
    __shared__ unsigned short As[128 * 40];
    __shared__ unsigned short Bs[128 * 40];
    const int tid = threadIdx.x;
    const int w = tid >> 6, lane = tid & 63, l15 = lane & 15, quad = lane >> 4;
    const int wm = w & 1, wn = w >> 1;
    const int r0 = blockIdx.x * 128;
    const int c0 = blockIdx.y * 128;

    f32x4 zero = {0.0f, 0.0f, 0.0f, 0.0f};
    f32x4 acc[4][4];
    for (int i = 0; i < 4; i++)
        for (int j = 0; j < 4; j++) acc[i][j] = zero;

    const int srow = tid >> 1;
    const int scol = (tid & 1) * 16;

    for (int k0 = 0; k0 < 512; k0 += 32) {
        const unsigned short* pa = Ob + (size_t)(r0 + srow) * 512 + k0 + scol;
        const unsigned short* pb = Wob + (size_t)(c0 + srow) * 512 + k0 + scol;
        uint4 a0 = *reinterpret_cast<const uint4*>(pa);
        uint4 a1 = *reinterpret_cast<const uint4*>(pa + 8);
        uint4 b0 = *reinterpret_cast<const uint4*>(pb);
        uint4 b1 = *reinterpret_cast<const uint4*>(pb + 8);
        *reinterpret_cast<uint4*>(As + srow * 40 + scol) = a0;
        *reinterpret_cast<uint4*>(As + srow * 40 + scol + 8) = a1;
        *reinterpret_cast<uint4*>(Bs + srow * 40 + scol) = b0;
        *reinterpret_cast<uint4*>(Bs + srow * 40 + scol + 8) = b1;
        __syncthreads();
        bf16x8 af[4], bfr[4];
        for (int mi = 0; mi < 4; mi++)
            af[mi] = *reinterpret_cast<const bf16x8*>(As + (wm * 64 + mi * 16 + l15) * 40 + quad * 8);
        for (int ni = 0; ni < 4; ni++)
            bfr[ni] = *reinterpret_cast<const bf16x8*>(Bs + (wn * 64 + ni * 16 + l15) * 40 + quad * 8);
        for (int mi = 0; mi < 4; mi++)
            for (int ni = 0; ni < 4; ni++)
                acc[mi][ni] = __builtin_amdgcn_mfma_f32_16x16x32_bf16(af[mi], bfr[ni], acc[mi][ni], 0, 0, 0);
        __syncthreads();
    }

    for (int mi = 0; mi < 4; mi++) {
        int grow_base = r0 + wm * 64 + mi * 16 + quad * 4;
        for (int ni = 0; ni < 4; ni++) {
            int gcol = c0 + wn * 64 + ni * 16 + l15;
            float bias = bo[gcol];
            for (int r = 0; r < 4; r++) {
                int grow = grow_base + r;
                out[(size_t)grow * 512 + gcol] = acc[mi][ni][r] + bias;
            }
        }
    }
}

extern "C" void kernel_launch(void* const* d_in, const int* in_sizes, int n_in,
                              void* d_out, int out_size, void* d_ws, size_t ws_size,
                              hipStream_t stream) {
    (void)in_sizes; (void)n_in; (void)out_size; (void)ws_size;
    const float* x    = (const float*)d_in[0];
    const float* mask = (const float*)d_in[1];
    const float* wq   = (const float*)d_in[2];
    const float* bq   = (const float*)d_in[3];
    const float* wk   = (const float*)d_in[4];
    const float* bk   = (const float*)d_in[5];
    const float* wv   = (const float*)d_in[6];
    const float* bv   = (const float*)d_in[7];
    const float* wo   = (const float*)d_in[8];
    const float* bo   = (const float*)d_in[9];
    float* out = (float*)d_out;

    char* ws = (char*)d_ws;
    unsigned short* Qb   = (unsigned short*)(ws);                  // 8 MiB
    unsigned short* Kb   = (unsigned short*)(ws + 8388608);        // 8 MiB
    unsigned short* Vtb  = (unsigned short*)(ws + 16777216);       // 8 MiB
    unsigned short* XO   = (unsigned short*)(ws + 25165824);       // 8 MiB: Xb then Obuf (aliased)
    unsigned short* Wc   = (unsigned short*)(ws + 33554432);       // 2 MiB: wq|wk|wv|wo bf16
    unsigned long long* Mbits = (unsigned long long*)(ws + 35651584); // 1 MiB

    pack_mask<<<8192, 256, 0, stream>>>(mask, Mbits);
    cast_all<<<dim3(2048, 5), 256, 0, stream>>>(x, wq, wk, wv, wo, XO, Wc);
    qkv_gemm<<<dim3(64, 12), 256, 0, stream>>>(XO, Wc, bq, bk, bv, Qb, Kb, Vtb);
    attn_kernel<<<dim3(16, 8, 8), 256, 0, stream>>>(Qb, Kb, Vtb, Mbits, XO /*Obuf*/);
    out_gemm<<<dim3(64, 4), 256, 0, stream>>>(XO /*Obuf*/, Wc + 3 * 262144, bo, out);
}

// Round 7
// 293.009 us; speedup vs baseline: 1.0415x; 1.0065x over previous
//
#include <hip/hip_runtime.h>
#include <cstdint>
#include <cstddef>

#define NHEAD 8
#define SLEN 1024

typedef __bf16 bf16x8 __attribute__((ext_vector_type(8)));
typedef float f32x4 __attribute__((ext_vector_type(4)));

__device__ inline unsigned short f2bf(float f) {
    union { float f; unsigned int u; } v; v.f = f;
    unsigned int u = v.u;
    unsigned int rounded = u + 0x7fffu + ((u >> 16) & 1u);
    return (unsigned short)(rounded >> 16);
}

__device__ inline unsigned int pack2(float a, float b) {
    return (unsigned int)f2bf(a) | ((unsigned int)f2bf(b) << 16);
}

__device__ inline uint4 cvt8(const float* __restrict__ p) {
    float4 a = *reinterpret_cast<const float4*>(p);
    float4 b = *reinterpret_cast<const float4*>(p + 4);
    uint4 r;
    r.x = pack2(a.x, a.y);
    r.y = pack2(a.z, a.w);
    r.z = pack2(b.x, b.y);
    r.w = pack2(b.z, b.w);
    return r;
}

// ---------------- mask bit-packing ----------------
__global__ __launch_bounds__(256) void pack_mask(
    const float* __restrict__ mask, unsigned long long* __restrict__ bits)
{
    int wid = (blockIdx.x * 256 + threadIdx.x) >> 6;
    int lane = threadIdx.x & 63;
    for (int s = 0; s < 4; s++) {
        size_t seg = (size_t)wid * 4 + s;
        float mv = mask[seg * 64 + lane];
        unsigned long long bb = __ballot(mv != 0.0f);
        if (lane == 0) bits[seg] = bb;
    }
}

// ---------------- f32 -> bf16 pre-cast (X + 4 weights) ----------------
__global__ __launch_bounds__(256) void cast_all(
    const float* __restrict__ X,
    const float* __restrict__ wq, const float* __restrict__ wk,
    const float* __restrict__ wv, const float* __restrict__ wo,
    unsigned short* __restrict__ Xb, unsigned short* __restrict__ Wc)
{
    int y = blockIdx.y;
    const float* src;
    unsigned short* dst;
    int n;
    if (y == 0) { src = X;  dst = Xb; n = 8192 * 512; }
    else {
        src = (y == 1) ? wq : (y == 2) ? wk : (y == 3) ? wv : wo;
        dst = Wc + (size_t)(y - 1) * 262144;
        n = 262144;
    }
    int i = (blockIdx.x * 256 + threadIdx.x) * 8;
    if (i + 8 <= n) {
        uint4 v = cvt8(src + i);
        *reinterpret_cast<uint4*>(dst + i) = v;
    }
}

// ---------------- fused QKV projection GEMM (bf16 in) ----------------
__global__ __launch_bounds__(256) void qkv_gemm(
    const unsigned short* __restrict__ Xb,
    const unsigned short* __restrict__ Wc,
    const float* __restrict__ bq, const float* __restrict__ bk,
    const float* __restrict__ bv,
    unsigned short* __restrict__ Qb, unsigned short* __restrict__ Kb,
    unsigned short* __restrict__ Vtb)
{
    __shared__ unsigned short As[17408];
    unsigned short* Bs = As + 128 * 40;
    const int tid = threadIdx.x;
    const int w = tid >> 6, lane = tid & 63, l15 = lane & 15, quad = lane >> 4;
    const int wm = w & 1, wn = w >> 1;
    const int r0 = blockIdx.x * 128;
    const int ytile = blockIdx.y;
    const int c0 = ytile * 128;
    const unsigned short* Wsel = Wc + (size_t)(ytile >> 2) * 262144;
    const int cw = c0 & 511;

    f32x4 zero = {0.0f, 0.0f, 0.0f, 0.0f};
    f32x4 acc[4][4];
    for (int i = 0; i < 4; i++)
        for (int j = 0; j < 4; j++) acc[i][j] = zero;

    const int srow = tid >> 1;
    const int scol = (tid & 1) * 16;

    for (int k0 = 0; k0 < 512; k0 += 32) {
        const unsigned short* pa = Xb + (size_t)(r0 + srow) * 512 + k0 + scol;
        const unsigned short* pb = Wsel + (size_t)(cw + srow) * 512 + k0 + scol;
        uint4 a0 = *reinterpret_cast<const uint4*>(pa);
        uint4 a1 = *reinterpret_cast<const uint4*>(pa + 8);
        uint4 b0 = *reinterpret_cast<const uint4*>(pb);
        uint4 b1 = *reinterpret_cast<const uint4*>(pb + 8);
        *reinterpret_cast<uint4*>(As + srow * 40 + scol) = a0;
        *reinterpret_cast<uint4*>(As + srow * 40 + scol + 8) = a1;
        *reinterpret_cast<uint4*>(Bs + srow * 40 + scol) = b0;
        *reinterpret_cast<uint4*>(Bs + srow * 40 + scol + 8) = b1;
        __syncthreads();
        bf16x8 af[4], bfr[4];
        for (int mi = 0; mi < 4; mi++)
            af[mi] = *reinterpret_cast<const bf16x8*>(As + (wm * 64 + mi * 16 + l15) * 40 + quad * 8);
        for (int ni = 0; ni < 4; ni++)
            bfr[ni] = *reinterpret_cast<const bf16x8*>(Bs + (wn * 64 + ni * 16 + l15) * 40 + quad * 8);
        for (int mi = 0; mi < 4; mi++)
            for (int ni = 0; ni < 4; ni++)
                acc[mi][ni] = __builtin_amdgcn_mfma_f32_16x16x32_bf16(af[mi], bfr[ni], acc[mi][ni], 0, 0, 0);
        __syncthreads();
    }

    const int bb = r0 >> 10;
    const int s0 = r0 & 1023;

    if (ytile < 8) {
        const bool isQ = (ytile < 4);
        const float* bias = isQ ? bq : bk;
        unsigned short* dst = isQ ? Qb : Kb;
        const float scale = isQ ? 0.125f : 1.0f;
        const int h0 = cw >> 6;
        for (int mi = 0; mi < 4; mi++) {
            for (int ni = 0; ni < 4; ni++) {
                int col = wn * 64 + ni * 16 + l15;
                float bsv = bias[cw + col];
                for (int r = 0; r < 4; r++) {
                    int s_local = wm * 64 + mi * 16 + quad * 4 + r;
                    As[s_local * 136 + col] = f2bf((acc[mi][ni][r] + bsv) * scale);
                }
            }
        }
        __syncthreads();
        for (int p = 0; p < 2; p++) {
            size_t base = (((size_t)(bb * NHEAD + h0 + p)) << 10) + s0;
            for (int i = 0; i < 4; i++) {
                int flat = i * 256 + tid;
                int row = flat >> 3;
                int ch = flat & 7;
                uint4 vv = *reinterpret_cast<const uint4*>(As + row * 136 + p * 64 + ch * 8);
                *reinterpret_cast<uint4*>(dst + (base + row) * 64 + ch * 8) = vv;
            }
        }
    } else {
        const int h_base = (c0 - 1024) >> 6;
        for (int p = 0; p < 2; p++) {
            __syncthreads();
            if (wn == p) {
                for (int mi = 0; mi < 4; mi++) {
                    for (int ni = 0; ni < 4; ni++) {
                        int d_local = ni * 16 + l15;
                        float bias = bv[(h_base + p) * 64 + d_local];
                        for (int r = 0; r < 4; r++) {
                            int s_local = wm * 64 + mi * 16 + quad * 4 + r;
                            As[d_local * 136 + s_local] = f2bf(acc[mi][ni][r] + bias);
                        }
                    }
                }
            }
            __syncthreads();
            int sidx = (tid & 15) * 8;
            int drow = tid >> 4;
            for (int dg = 0; dg < 4; dg++) {
                int d = dg * 16 + drow;
                size_t dst = ((size_t)(bb * NHEAD + h_base + p) * 64 + d) * 1024 + s0;
                uint4 vv = *reinterpret_cast<const uint4*>(As + d * 136 + sidx);
                *reinterpret_cast<uint4*>(Vtb + dst + sidx) = vv;
            }
        }
    }
}

// ---------------- flash attention: transposed MFMAs (S^T / O^T) ----------------
// Wave = 16 query rows; lane l15 = THE query row for this lane (all softmax
// state per-lane scalar). S^T = K·Q^T (A=K, B=Q): C col = q = l15,
// row = key = quad*4+r in subtile ni. Softmax: in-lane tree over 16 regs +
// shfl_xor(16,32). P^T via wave-private LDS row [q][key] (ds_write_b64 x4,
// ds_read_b128 x2, no barrier). O^T = V^T·P^T: col = q = l15 -> alpha
// rescale is per-lane VALU. No __syncthreads anywhere.
__global__ __launch_bounds__(256) void attn_kernel(
    const unsigned short* __restrict__ Qb,
    const unsigned short* __restrict__ Kb,
    const unsigned short* __restrict__ Vtb,
    const unsigned long long* __restrict__ Mbits,
    unsigned short* __restrict__ Ob)
{
    __shared__ __bf16 Ps[4 * 16 * 72];

    const int tid = threadIdx.x;
    const int w = tid >> 6, lane = tid & 63, l15 = lane & 15, quad = lane >> 4;
    const int qt = blockIdx.x, h = blockIdx.y, b = blockIdx.z;
    const int q = qt * 64 + w * 16 + l15;          // this lane's query row
    const size_t bh = (size_t)(b * NHEAD + h);
    const unsigned short* Qg = Qb + bh * SLEN * 64;
    const unsigned short* Kg = Kb + bh * SLEN * 64;
    const unsigned short* Vg = Vtb + bh * 64 * SLEN;
    const unsigned long long* mrow = Mbits + ((size_t)b * SLEN + q) * 16;
    __bf16* Prow = Ps + (w * 16 + l15) * 72;       // this lane's P^T row (q fixed)

    // Q B-frag: n = q = l15, k = quad*8+j
    bf16x8 bq0 = *reinterpret_cast<const bf16x8*>(Qg + (size_t)q * 64 + quad * 8);
    bf16x8 bq1 = *reinterpret_cast<const bf16x8*>(Qg + (size_t)q * 64 + 32 + quad * 8);

    float m_i = -3.0e38f, l_i = 0.0f;
    f32x4 zero = {0.0f, 0.0f, 0.0f, 0.0f};
    f32x4 Oacc[4];
    for (int nd = 0; nd < 4; nd++) Oacc[nd] = zero;

    for (int kt = 0; kt < SLEN / 64; kt++) {
        const int k0 = kt * 64;

        // one mask word per lane (64 key bits for this lane's q row)
        unsigned long long mw = mrow[kt] >> (quad * 4);
        unsigned int mlo = (unsigned int)mw;
        unsigned int mhi = (unsigned int)(mw >> 32);

        // S^T = K Q^T : A = K (m = key), B = Q (n = q)
        f32x4 st[4];
        for (int ni = 0; ni < 4; ni++) {
            const unsigned short* kp = Kg + (size_t)(k0 + ni * 16 + l15) * 64 + quad * 8;
            bf16x8 ka0 = *reinterpret_cast<const bf16x8*>(kp);
            bf16x8 ka1 = *reinterpret_cast<const bf16x8*>(kp + 32);
            f32x4 z = zero;
            z = __builtin_amdgcn_mfma_f32_16x16x32_bf16(ka0, bq0, z, 0, 0, 0);
            z = __builtin_amdgcn_mfma_f32_16x16x32_bf16(ka1, bq1, z, 0, 0, 0);
            st[ni] = z;
        }
        // mask: key = k0 + ni*16 + quad*4 + r -> bit (ni*16+r) of mw>>(quad*4)
        for (int r = 0; r < 4; r++) {
            st[0][r] = ((mlo >> r) & 1u)        ? -1.0e7f : st[0][r];
            st[1][r] = ((mlo >> (16 + r)) & 1u) ? -1.0e7f : st[1][r];
            st[2][r] = ((mhi >> r) & 1u)        ? -1.0e7f : st[2][r];
            st[3][r] = ((mhi >> (16 + r)) & 1u) ? -1.0e7f : st[3][r];
        }
        // row max: in-lane tree over 16 values + combine quads (xor 16, 32)
        float t01 = fmaxf(fmaxf(st[0][0], st[0][1]), fmaxf(st[0][2], st[0][3]));
        float t23 = fmaxf(fmaxf(st[1][0], st[1][1]), fmaxf(st[1][2], st[1][3]));
        float t45 = fmaxf(fmaxf(st[2][0], st[2][1]), fmaxf(st[2][2], st[2][3]));
        float t67 = fmaxf(fmaxf(st[3][0], st[3][1]), fmaxf(st[3][2], st[3][3]));
        float t = fmaxf(fmaxf(t01, t23), fmaxf(t45, t67));
        t = fmaxf(t, __shfl_xor(t, 16));
        t = fmaxf(t, __shfl_xor(t, 32));
        float mnew = fmaxf(m_i, t);
        float alpha = __expf(m_i - mnew);
        m_i = mnew;

        // p = exp(s - m), partial sum in-lane, pack to P^T row in LDS
        float psum = 0.0f;
        for (int ni = 0; ni < 4; ni++) {
            float p0 = __expf(st[ni][0] - mnew);
            float p1 = __expf(st[ni][1] - mnew);
            float p2 = __expf(st[ni][2] - mnew);
            float p3 = __expf(st[ni][3] - mnew);
            psum += (p0 + p1) + (p2 + p3);
            uint2 pk;
            pk.x = pack2(p0, p1);
            pk.y = pack2(p2, p3);
            *reinterpret_cast<uint2*>(Prow + ni * 16 + quad * 4) = pk;
        }
        psum += __shfl_xor(psum, 16);
        psum += __shfl_xor(psum, 32);
        l_i = l_i * alpha + psum;
        for (int nd = 0; nd < 4; nd++)
            for (int r = 0; r < 4; r++)
                Oacc[nd][r] *= alpha;

        // P^T B-frag: n = q = l15 (this lane's LDS row), k = quad*8+j
        bf16x8 bp0 = *reinterpret_cast<const bf16x8*>(Prow + quad * 8);
        bf16x8 bp1 = *reinterpret_cast<const bf16x8*>(Prow + 32 + quad * 8);
        // O^T += V^T P^T : A = V^T (m = d), keys contiguous
        for (int nd = 0; nd < 4; nd++) {
            const unsigned short* vp = Vg + (size_t)(nd * 16 + l15) * SLEN + k0 + quad * 8;
            bf16x8 va0 = *reinterpret_cast<const bf16x8*>(vp);
            bf16x8 va1 = *reinterpret_cast<const bf16x8*>(vp + 32);
            Oacc[nd] = __builtin_amdgcn_mfma_f32_16x16x32_bf16(va0, bp0, Oacc[nd], 0, 0, 0);
            Oacc[nd] = __builtin_amdgcn_mfma_f32_16x16x32_bf16(va1, bp1, Oacc[nd], 0, 0, 0);
        }
    }

    // epilogue: O^T col = q = l15 (per-lane), row = d = nd*16 + quad*4 + r
    float inv = 1.0f / l_i;
    for (int nd = 0; nd < 4; nd++) {
        uint2 o;
        o.x = pack2(Oacc[nd][0] * inv, Oacc[nd][1] * inv);
        o.y = pack2(Oacc[nd][2] * inv, Oacc[nd][3] * inv);
        *reinterpret_cast<uint2*>(Ob + ((size_t)(b * SLEN + q)) * 512 + h * 64 + nd * 16 + quad * 4) = o;
    }
}

// ---------------- output projection GEMM (bf16 in, f32 out) ----------------
__global__ __launch_bounds__(256) void out_gemm(
    const unsigned short* __restrict__ Ob,
    const unsigned short* __restrict__ Wob,
    const float* __restrict__ bo,
    float* __restrict__ out)
{
    __shared__ unsigned short As[128 * 40];
    __shared__ unsigned short Bs[128 * 40];
    const int tid = threadIdx.x;
    const int w = tid >> 6, lane = tid & 63, l15 = lane & 15, quad = lane >> 4;
    const int wm = w & 1, wn = w >> 1;
    const int r0 = blockIdx.x * 128;
    const int c0 = blockIdx.y * 128;

    f32x4 zero = {0.0f, 0.0f, 0.0f, 0.0f};
    f32x4 acc[4][4];
    for (int i = 0; i < 4; i++)
        for (int j = 0; j < 4; j++) acc[i][j] = zero;

    const int srow = tid >> 1;
    const int scol = (tid & 1) * 16;

    for (int k0 = 0; k0 < 512; k0 += 32) {
        const unsigned short* pa = Ob + (size_t)(r0 + srow) * 512 + k0 + scol;
        const unsigned short* pb = Wob + (size_t)(c0 + srow) * 512 + k0 + scol;
        uint4 a0 = *reinterpret_cast<const uint4*>(pa);
        uint4 a1 = *reinterpret_cast<const uint4*>(pa + 8);
        uint4 b0 = *reinterpret_cast<const uint4*>(pb);
        uint4 b1 = *reinterpret_cast<const uint4*>(pb + 8);
        *reinterpret_cast<uint4*>(As + srow * 40 + scol) = a0;
        *reinterpret_cast<uint4*>(As + srow * 40 + scol + 8) = a1;
        *reinterpret_cast<uint4*>(Bs + srow * 40 + scol) = b0;
        *reinterpret_cast<uint4*>(Bs + srow * 40 + scol + 8) = b1;
        __syncthreads();
        bf16x8 af[4], bfr[4];
        for (int mi = 0; mi < 4; mi++)
            af[mi] = *reinterpret_cast<const bf16x8*>(As + (wm * 64 + mi * 16 + l15) * 40 + quad * 8);
        for (int ni = 0; ni < 4; ni++)
            bfr[ni] = *reinterpret_cast<const bf16x8*>(Bs + (wn * 64 + ni * 16 + l15) * 40 + quad * 8);
        for (int mi = 0; mi < 4; mi++)
            for (int ni = 0; ni < 4; ni++)
                acc[mi][ni] = __builtin_amdgcn_mfma_f32_16x16x32_bf16(af[mi], bfr[ni], acc[mi][ni], 0, 0, 0);
        __syncthreads();
    }

    for (int mi = 0; mi < 4; mi++) {
        int grow_base = r0 + wm * 64 + mi * 16 + quad * 4;
        for (int ni = 0; ni < 4; ni++) {
            int gcol = c0 + wn * 64 + ni * 16 + l15;
            float bias = bo[gcol];
            for (int r = 0; r < 4; r++) {
                int grow = grow_base + r;
                out[(size_t)grow * 512 + gcol] = acc[mi][ni][r] + bias;
            }
        }
    }
}

extern "C" void kernel_launch(void* const* d_in, const int* in_sizes, int n_in,
                              void* d_out, int out_size, void* d_ws, size_t ws_size,
                              hipStream_t stream) {
    (void)in_sizes; (void)n_in; (void)out_size; (void)ws_size;
    const float* x    = (const float*)d_in[0];
    const float* mask = (const float*)d_in[1];
    const float* wq   = (const float*)d_in[2];
    const float* bq   = (const float*)d_in[3];
    const float* wk   = (const float*)d_in[4];
    const float* bk   = (const float*)d_in[5];
    const float* wv   = (const float*)d_in[6];
    const float* bv   = (const float*)d_in[7];
    const float* wo   = (const float*)d_in[8];
    const float* bo   = (const float*)d_in[9];
    float* out = (float*)d_out;

    char* ws = (char*)d_ws;
    unsigned short* Qb   = (unsigned short*)(ws);                  // 8 MiB
    unsigned short* Kb   = (unsigned short*)(ws + 8388608);        // 8 MiB
    unsigned short* Vtb  = (unsigned short*)(ws + 16777216);       // 8 MiB
    unsigned short* XO   = (unsigned short*)(ws + 25165824);       // 8 MiB: Xb then Obuf
    unsigned short* Wc   = (unsigned short*)(ws + 33554432);       // 2 MiB
    unsigned long long* Mbits = (unsigned long long*)(ws + 35651584); // 1 MiB

    pack_mask<<<8192, 256, 0, stream>>>(mask, Mbits);
    cast_all<<<dim3(2048, 5), 256, 0, stream>>>(x, wq, wk, wv, wo, XO, Wc);
    qkv_gemm<<<dim3(64, 12), 256, 0, stream>>>(XO, Wc, bq, bk, bv, Qb, Kb, Vtb);
    attn_kernel<<<dim3(16, 8, 8), 256, 0, stream>>>(Qb, Kb, Vtb, Mbits, XO /*Obuf*/);
    out_gemm<<<dim3(64, 4), 256, 0, stream>>>(XO /*Obuf*/, Wc + 3 * 262144, bo, out);
}